// Round 4
// baseline (334.633 us; speedup 1.0000x reference)
//
#include <hip/hip_runtime.h>
#include <hip/hip_bf16.h>
#include <hip/hip_cooperative_groups.h>

namespace cg = cooperative_groups;

// Problem constants (match reference)
#define BB 8
#define NN 256
#define FF 64      // F_NODE
#define EE 16      // F_EDGE
#define MM 64      // M_MSG
#define G3 192     // 3*F_NODE
#define OUTD 128
#define ROWS (BB*NN)   // 2048
#define MAXD 64        // padded neighbor cap (Binomial(256,0.1): mean 25.6; 64 ~8 sigma)
#define RPB  4         // rows per block (coop kernel)
#define NBLK (ROWS/RPB) // 512 blocks -> needs only 2 blocks/CU co-resident (2x margin)

__device__ __forceinline__ float sigmoidf_(float x) {
    return 1.0f / (1.0f + __expf(-x));
}

// ===========================================================================
// PATH A: single cooperative kernel. Per-block state (nbr list, edge feats,
// h) lives in LDS across all 3 passes; only hn round-trips global (double-
// buffered across grid.sync()).
// LDS ~28.1 KB, VGPR<=128 (launch_bounds(256,4)) -> 4 blocks/CU possible,
// 2 needed.
// ===========================================================================
__global__ __launch_bounds__(256, 4) void k_all(
    const float* __restrict__ nodes, const float* __restrict__ edges,
    const float* __restrict__ Wmsg, const float* __restrict__ bmsg,
    const float* __restrict__ Wi,   const float* __restrict__ Wh,
    const float* __restrict__ bi,   const float* __restrict__ bh,
    const float* __restrict__ Wg,   const float* __restrict__ bg,
    const float* __restrict__ We,   const float* __restrict__ be,
    float* __restrict__ out, float* __restrict__ hnA, float* __restrict__ hnB)
{
    cg::grid_group grid = cg::this_grid();

    const int tid  = threadIdx.x;
    const int lane = tid & 63;
    const int w    = tid >> 6;          // wave 0..3
    const int gr0  = blockIdx.x * RPB;  // first global row of this block
    const int b    = gr0 >> 8;          // batch (RPB divides 256 -> uniform)

    __shared__ int   snbr[RPB][MAXD];        // 1 KB
    __shared__ int   sdeg[RPB];
    __shared__ int   wcnt[RPB][4];
    __shared__ float efeat[RPB][MAXD][EE];   // 16 KB
    __shared__ float sh[RPB][FF];            // h state
    __shared__ float sx[RPB][FF];            // pristine nodes
    __shared__ float smsg[RPB][MM];
    __shared__ float gates[RPB][6][FF];      // 6 KB: [r][0..2]=gi, [3..5]=gh
    __shared__ float red[RPB][OUTD];         // 2 KB

    // ---------------- prep: edge detect + ballot-scan compaction ------------
    bool pr[RPB];
    unsigned long long mb[RPB];
    #pragma unroll
    for (int r = 0; r < RPB; ++r) {
        const float4* ep = (const float4*)(edges + (((size_t)(gr0 + r)) * NN + tid) * EE);
        float4 a = ep[0], b4 = ep[1], c4 = ep[2], d4 = ep[3];
        float s = a.x+a.y+a.z+a.w + b4.x+b4.y+b4.z+b4.w
                + c4.x+c4.y+c4.z+c4.w + d4.x+d4.y+d4.z+d4.w;
        pr[r] = (s != 0.0f);
        mb[r] = __ballot(pr[r]);
        if (lane == 0) wcnt[r][w] = __popcll(mb[r]);
    }
    {   // nodes -> sh (working h) and sx (pristine); 256 thr = 4 rows x 64
        int r = tid >> 6, k = tid & 63;
        float v = nodes[(size_t)(gr0 + r) * FF + k];
        sh[r][k] = v; sx[r][k] = v;
    }
    __syncthreads();

    {
        unsigned long long low = (1ull << lane) - 1ull;
        #pragma unroll
        for (int r = 0; r < RPB; ++r) {
            int base = 0;
            #pragma unroll
            for (int q = 0; q < 4; ++q) base += (q < w) ? wcnt[r][q] : 0;
            int sl = base + __popcll(mb[r] & low);
            if (pr[r] && sl < MAXD) snbr[r][sl] = tid;
        }
        if (tid < RPB) {
            int tot = wcnt[tid][0] + wcnt[tid][1] + wcnt[tid][2] + wcnt[tid][3];
            sdeg[tid] = (tot < MAXD) ? tot : MAXD;
        }
    }
    __syncthreads();

    // gather edge features into LDS (persist across all passes)
    #pragma unroll
    for (int r = 0; r < RPB; ++r) {
        int cnt = sdeg[r] * EE;
        for (int i = tid; i < cnt; i += 256) {
            int slot = i >> 4, k = i & 15;
            efeat[r][slot][k] =
                edges[(((size_t)(gr0 + r)) * NN + snbr[r][slot]) * EE + k];
        }
    }

    // hn0 = nodes @ W_n + b_msg
    {
        int r = tid >> 6, tt = tid & 63;
        float acc = bmsg[tt];
        #pragma unroll 8
        for (int k = 0; k < FF; ++k) acc += sx[r][k] * Wmsg[k * MM + tt];
        hnA[(size_t)(gr0 + r) * MM + tt] = acc;
    }
    // zero the output accumulator before any readout atomics (post grid.sync)
    if (blockIdx.x == 0) {
        #pragma unroll
        for (int i = 0; i < (BB * OUTD) / 256; ++i) out[i * 256 + tid] = 0.0f;
    }

    // W_e column (rows 64..79 of W_msg) -> registers, reused all passes
    float we[EE];
    #pragma unroll
    for (int k = 0; k < EE; ++k) we[k] = Wmsg[(FF + k) * MM + lane];

    grid.sync();   // hn0 + out-zero visible everywhere

    // ---------------- 3 message passes --------------------------------------
    for (int p = 0; p < 3; ++p) {
        const float* __restrict__ hin  = (p & 1) ? hnB : hnA;
        float*       __restrict__ hout = (p & 1) ? hnA : hnB;

        // msg: wave w owns row w
        {
            int d = sdeg[w];
            const float* hb = hin + (size_t)b * NN * MM;
            float acc = 0.0f;
            for (int s = 0; s < d; ++s) {
                int j = snbr[w][s];
                float term = hb[j * MM + lane];
                #pragma unroll
                for (int k = 0; k < EE; ++k) term += efeat[w][s][k] * we[k];
                acc += fmaxf(term, 0.0f);
            }
            smsg[w][lane] = acc;
        }
        __syncthreads();

        // gates: 6 tasks (3 gi-gates from msg@Wi, 3 gh-gates from h@Wh),
        // each task loads its weight column ONCE and applies to all 4 rows.
        for (int q = w; q < 6; q += 4) {
            float a0, a1, a2, a3;
            if (q < 3) {
                a0 = a1 = a2 = a3 = bi[q * FF + lane];
                #pragma unroll 4
                for (int k = 0; k < FF; ++k) {
                    float wgt = Wi[k * G3 + q * FF + lane];
                    a0 += smsg[0][k] * wgt; a1 += smsg[1][k] * wgt;
                    a2 += smsg[2][k] * wgt; a3 += smsg[3][k] * wgt;
                }
            } else {
                int g = q - 3;
                a0 = a1 = a2 = a3 = bh[g * FF + lane];
                #pragma unroll 4
                for (int k = 0; k < FF; ++k) {
                    float wgt = Wh[k * G3 + g * FF + lane];
                    a0 += sh[0][k] * wgt; a1 += sh[1][k] * wgt;
                    a2 += sh[2][k] * wgt; a3 += sh[3][k] * wgt;
                }
            }
            gates[0][q][lane] = a0; gates[1][q][lane] = a1;
            gates[2][q][lane] = a2; gates[3][q][lane] = a3;
        }
        __syncthreads();

        // combine: 256 threads = 4 rows x 64 features
        {
            int r = tid >> 6, tt = tid & 63;
            float rr = sigmoidf_(gates[r][0][tt] + gates[r][3][tt]);
            float zz = sigmoidf_(gates[r][1][tt] + gates[r][4][tt]);
            float ng = tanhf(gates[r][2][tt] + rr * gates[r][5][tt]);
            float hold = sh[r][tt];
            float hnew = (1.0f - zz) * ng + zz * hold;
            if (sdeg[r] == 0) hnew = hold;     // node_mask scatter semantics
            sh[r][tt] = hnew;
        }
        __syncthreads();

        if (p < 2) {
            // hn for next pass: h_new @ W_n + b_msg
            int r = tid >> 6, tt = tid & 63;
            float acc = bmsg[tt];
            #pragma unroll 8
            for (int k = 0; k < FF; ++k) acc += sh[r][k] * Wmsg[k * MM + tt];
            hout[(size_t)(gr0 + r) * MM + tt] = acc;
            grid.sync();
        }
    }

    // ---------------- gated readout -----------------------------------------
    {
        int r0 = tid >> 7, o = tid & 127;
        #pragma unroll
        for (int rr = 0; rr < RPB; rr += 2) {
            int r = r0 + rr;
            float g = bg[o], e = be[o];
            #pragma unroll 4
            for (int k = 0; k < FF; ++k) {
                float hk = sh[r][k];
                g += hk * Wg[k * OUTD + o];
                e += hk * We[k * OUTD + o];
            }
            #pragma unroll 4
            for (int k = 0; k < FF; ++k) g += sx[r][k] * Wg[(FF + k) * OUTD + o];
            red[r][o] = (sdeg[r] != 0) ? sigmoidf_(g) * e : 0.0f;
        }
        __syncthreads();
        if (tid < OUTD)
            atomicAdd(&out[b * OUTD + tid],
                      red[0][tid] + red[1][tid] + red[2][tid] + red[3][tid]);
    }
}

// ===========================================================================
// PATH B (fallback, round-2 proven): k_prep + 3x k_pass
// ===========================================================================
__global__ __launch_bounds__(256) void k_prep(
    const float* __restrict__ nodes, const float* __restrict__ edges,
    const float* __restrict__ Wmsg, const float* __restrict__ bmsg,
    int* __restrict__ deg, int* __restrict__ nbr,
    float* __restrict__ h, float* __restrict__ hn)
{
    int row = blockIdx.x;
    int tid = threadIdx.x;
    int lane = tid & 63, wv = tid >> 6;
    __shared__ int wcnt[4];
    __shared__ float snode[FF];

    const float4* ep = (const float4*)(edges + (((size_t)row) * NN + tid) * EE);
    float4 a = ep[0], b4 = ep[1], c4 = ep[2], d4 = ep[3];
    float s = a.x+a.y+a.z+a.w + b4.x+b4.y+b4.z+b4.w
            + c4.x+c4.y+c4.z+c4.w + d4.x+d4.y+d4.z+d4.w;
    bool pred = (s != 0.0f);
    unsigned long long m = __ballot(pred);
    if (lane == 0) wcnt[wv] = __popcll(m);
    if (tid < FF) snode[tid] = nodes[(size_t)row * FF + tid];
    __syncthreads();

    int base = 0;
    #pragma unroll
    for (int q = 0; q < 4; ++q) base += (q < wv) ? wcnt[q] : 0;
    int slot = base + __popcll(m & ((1ull << lane) - 1ull));
    if (pred && slot < MAXD) nbr[row * MAXD + slot] = tid;

    if (tid == 0) {
        int tot = wcnt[0] + wcnt[1] + wcnt[2] + wcnt[3];
        deg[row] = (tot < MAXD) ? tot : MAXD;
    }
    if (tid < FF) h[row * FF + tid] = snode[tid];
    if (tid < MM) {
        float acc = bmsg[tid];
        #pragma unroll 8
        for (int k = 0; k < FF; ++k) acc += snode[k] * Wmsg[k * MM + tid];
        hn[row * MM + tid] = acc;
    }
}

__global__ __launch_bounds__(256) void k_pass(
    const float* __restrict__ edges,
    const float* __restrict__ Wmsg, const float* __restrict__ bmsg,
    const float* __restrict__ Wi, const float* __restrict__ Wh,
    const float* __restrict__ bi, const float* __restrict__ bh,
    const float* __restrict__ nodes,
    const float* __restrict__ Wg, const float* __restrict__ bg,
    const float* __restrict__ We, const float* __restrict__ be,
    const int* __restrict__ deg, const int* __restrict__ nbr,
    const float* __restrict__ hn_in, float* __restrict__ hn_out,
    float* __restrict__ h, float* __restrict__ out, int last)
{
    int row = blockIdx.x, b = row >> 8;
    int tid = threadIdx.x;
    int w = tid >> 6, t = tid & 63;

    __shared__ int   snbr[MAXD];
    __shared__ float efeat[MAXD][EE];
    __shared__ float part[4][MM];
    __shared__ float smsg[MM];
    __shared__ float shold[FF];
    __shared__ float sx[FF];
    __shared__ float gI[3][FF], gH[3][FF];
    __shared__ float shnew[FF];
    __shared__ float eo[OUTD];

    int d = deg[row];
    if (tid < d)  snbr[tid]  = nbr[row * MAXD + tid];
    if (tid < FF) shold[tid] = h[row * FF + tid];
    if (last && tid < FF) sx[tid] = nodes[(size_t)row * FF + tid];

    float we[EE];
    #pragma unroll
    for (int k = 0; k < EE; ++k) we[k] = Wmsg[(FF + k) * MM + t];
    __syncthreads();

    for (int s4 = tid; s4 < d * EE; s4 += 256) {
        int slot = s4 >> 4, k = s4 & 15;
        efeat[slot][k] = edges[(((size_t)row) * NN + snbr[slot]) * EE + k];
    }
    __syncthreads();

    float acc = 0.0f;
    for (int s = w; s < d; s += 4) {
        int j = snbr[s];
        float term = hn_in[(((size_t)b) * NN + j) * MM + t];
        #pragma unroll
        for (int k = 0; k < EE; ++k) term += efeat[s][k] * we[k];
        acc += fmaxf(term, 0.0f);
    }
    part[w][t] = acc;
    __syncthreads();
    if (w == 0) smsg[t] = part[0][t] + part[1][t] + part[2][t] + part[3][t];
    __syncthreads();

    if (w < 3) {
        float gi = bi[w * FF + t], gh = bh[w * FF + t];
        #pragma unroll 4
        for (int k = 0; k < FF; ++k) {
            gi += smsg[k]  * Wi[k * G3 + w * FF + t];
            gh += shold[k] * Wh[k * G3 + w * FF + t];
        }
        gI[w][t] = gi; gH[w][t] = gh;
    }
    __syncthreads();

    if (w == 0) {
        float r  = sigmoidf_(gI[0][t] + gH[0][t]);
        float z  = sigmoidf_(gI[1][t] + gH[1][t]);
        float ng = tanhf(gI[2][t] + r * gH[2][t]);
        float hold = shold[t];
        float hnew = (1.0f - z) * ng + z * hold;
        if (d == 0) hnew = hold;
        shnew[t] = hnew;
        h[row * FF + t] = hnew;
    }
    __syncthreads();

    if (!last) {
        float p = 0.0f;
        #pragma unroll
        for (int kk = 0; kk < 16; ++kk) {
            int k = w * 16 + kk;
            p += shnew[k] * Wmsg[k * MM + t];
        }
        part[w][t] = p;
        __syncthreads();
        if (w == 0)
            hn_out[row * MM + t] = bmsg[t] + part[0][t] + part[1][t] + part[2][t] + part[3][t];
    } else {
        int o = tid & 127, half = tid >> 7;
        float g = 0.0f;
        if (half == 1) {
            float e = be[o];
            #pragma unroll 4
            for (int k = 0; k < FF; ++k) e += shnew[k] * We[k * OUTD + o];
            eo[o] = e;
        } else {
            g = bg[o];
            #pragma unroll 4
            for (int k = 0; k < FF; ++k) g += shnew[k] * Wg[k * OUTD + o];
            #pragma unroll 4
            for (int k = 0; k < FF; ++k) g += sx[k] * Wg[(FF + k) * OUTD + o];
        }
        __syncthreads();
        if (half == 0 && d != 0) {
            float val = sigmoidf_(g) * eo[o];
            atomicAdd(&out[b * OUTD + o], val);
        }
    }
}

// ---------------------------------------------------------------------------
extern "C" void kernel_launch(void* const* d_in, const int* in_sizes, int n_in,
                              void* d_out, int out_size, void* d_ws, size_t ws_size,
                              hipStream_t stream) {
    const float* nodes = (const float*)d_in[0];
    const float* edges = (const float*)d_in[1];
    const float* Wmsg  = (const float*)d_in[2];
    const float* bmsg  = (const float*)d_in[3];
    const float* Wi    = (const float*)d_in[4];
    const float* Wh    = (const float*)d_in[5];
    const float* bi    = (const float*)d_in[6];
    const float* bh    = (const float*)d_in[7];
    const float* Wg    = (const float*)d_in[8];
    const float* bg    = (const float*)d_in[9];
    const float* We    = (const float*)d_in[10];
    const float* be    = (const float*)d_in[11];
    float* out = (float*)d_out;
    char* ws = (char*)d_ws;

    // ---- Path A: cooperative, single dispatch -----------------------------
    // Deterministic occupancy pre-check (pure query; capture-safe).
    int occ = 0;
    hipError_t qe = hipOccupancyMaxActiveBlocksPerMultiprocessor(
        &occ, (const void*)k_all, 256, 0);
    if (qe == hipSuccess && occ * 256 >= NBLK) {
        float* hnA = (float*)ws;                 // 512 KB
        float* hnB = hnA + (size_t)ROWS * MM;    // 512 KB
        void* args[] = {
            (void*)&nodes, (void*)&edges, (void*)&Wmsg, (void*)&bmsg,
            (void*)&Wi, (void*)&Wh, (void*)&bi, (void*)&bh,
            (void*)&Wg, (void*)&bg, (void*)&We, (void*)&be,
            (void*)&out, (void*)&hnA, (void*)&hnB
        };
        hipError_t le = hipLaunchCooperativeKernel(
            (void*)k_all, dim3(NBLK), dim3(256), args, 0, stream);
        if (le == hipSuccess) return;
    }

    // ---- Path B: proven multi-kernel fallback -----------------------------
    int*   deg  = (int*)ws;
    int*   nbr  = (int*)(ws + 8192);
    float* h    = (float*)(ws + 8192 + (size_t)ROWS * MAXD * 4);
    float* hnA  = h   + (size_t)ROWS * FF;
    float* hnB  = hnA + (size_t)ROWS * MM;

    hipMemsetAsync(d_out, 0, (size_t)BB * OUTD * sizeof(float), stream);
    k_prep<<<ROWS, 256, 0, stream>>>(nodes, edges, Wmsg, bmsg, deg, nbr, h, hnA);
    k_pass<<<ROWS, 256, 0, stream>>>(edges, Wmsg, bmsg, Wi, Wh, bi, bh,
                                     nodes, Wg, bg, We, be, deg, nbr,
                                     hnA, hnB, h, out, 0);
    k_pass<<<ROWS, 256, 0, stream>>>(edges, Wmsg, bmsg, Wi, Wh, bi, bh,
                                     nodes, Wg, bg, We, be, deg, nbr,
                                     hnB, hnA, h, out, 0);
    k_pass<<<ROWS, 256, 0, stream>>>(edges, Wmsg, bmsg, Wi, Wh, bi, bh,
                                     nodes, Wg, bg, We, be, deg, nbr,
                                     hnA, hnB, h, out, 1);
}

// Round 5
// 144.530 us; speedup vs baseline: 2.3153x; 2.3153x over previous
//
#include <hip/hip_runtime.h>
#include <hip/hip_bf16.h>

// Problem constants (match reference)
#define BB 8
#define NN 256
#define FF 64      // F_NODE
#define EE 16      // F_EDGE
#define MM 64      // M_MSG
#define G3 192     // 3*F_NODE
#define OUTD 128
#define ROWS (BB*NN)   // 2048
#define MAXD 64        // padded neighbor cap (Binomial(256,0.1): mean 25.6; 64 ~8 sigma)

__device__ __forceinline__ float sigmoidf_(float x) {
    return 1.0f / (1.0f + __expf(-x));
}

// ---------------------------------------------------------------------------
// k_prep: one block per row. Edge detect + ballot-scan compaction,
// h init = nodes, hn0 = nodes @ W_n + b_msg. Block 0 zeroes d_out.
// ---------------------------------------------------------------------------
__global__ __launch_bounds__(256) void k_prep(
    const float* __restrict__ nodes, const float* __restrict__ edges,
    const float* __restrict__ Wmsg, const float* __restrict__ bmsg,
    int* __restrict__ deg, int* __restrict__ nbr,
    float* __restrict__ h, float* __restrict__ hn, float* __restrict__ out)
{
    int row = blockIdx.x;
    int tid = threadIdx.x;
    int lane = tid & 63, wv = tid >> 6;
    __shared__ int wcnt[4];
    __shared__ float snode[FF];

    const float4* ep = (const float4*)(edges + (((size_t)row) * NN + tid) * EE);
    float4 a = ep[0], b4 = ep[1], c4 = ep[2], d4 = ep[3];
    float s = a.x+a.y+a.z+a.w + b4.x+b4.y+b4.z+b4.w
            + c4.x+c4.y+c4.z+c4.w + d4.x+d4.y+d4.z+d4.w;
    bool pred = (s != 0.0f);
    unsigned long long m = __ballot(pred);
    if (lane == 0) wcnt[wv] = __popcll(m);
    if (tid < FF) snode[tid] = nodes[(size_t)row * FF + tid];
    __syncthreads();

    int base = 0;
    #pragma unroll
    for (int q = 0; q < 4; ++q) base += (q < wv) ? wcnt[q] : 0;
    int slot = base + __popcll(m & ((1ull << lane) - 1ull));
    if (pred && slot < MAXD) nbr[row * MAXD + slot] = tid;

    if (tid == 0) {
        int tot = wcnt[0] + wcnt[1] + wcnt[2] + wcnt[3];
        deg[row] = (tot < MAXD) ? tot : MAXD;
    }
    if (tid < FF) h[row * FF + tid] = snode[tid];
    if (tid < MM) {
        float acc = bmsg[tid];
        #pragma unroll 8
        for (int k = 0; k < FF; ++k) acc += snode[k] * Wmsg[k * MM + tid];
        hn[row * MM + tid] = acc;
    }
    // zero output accumulator (safe: out only touched by last pass's atomics,
    // which run after this kernel completes — stream ordering)
    if (row == 0) {
        #pragma unroll
        for (int i = 0; i < (BB * OUTD) / 256; ++i) out[i * 256 + tid] = 0.0f;
    }
}

// ---------------------------------------------------------------------------
// k_pass2: 2 rows per block, 512 threads (8 waves), 1024 blocks
//          -> 4 blocks/CU = 32 waves/CU (full occupancy).
// Gate weight columns loaded ONCE per block, applied to both rows
// (halves Wi/Wh L2 traffic vs 1 row/block).
// msg: 4 waves per row (short serial chains).
// ---------------------------------------------------------------------------
__global__ __launch_bounds__(512, 8) void k_pass2(
    const float* __restrict__ edges,
    const float* __restrict__ Wmsg, const float* __restrict__ bmsg,
    const float* __restrict__ Wi, const float* __restrict__ Wh,
    const float* __restrict__ bi, const float* __restrict__ bh,
    const float* __restrict__ nodes,
    const float* __restrict__ Wg, const float* __restrict__ bg,
    const float* __restrict__ We, const float* __restrict__ be,
    const int* __restrict__ deg, const int* __restrict__ nbr,
    const float* __restrict__ hn_in, float* __restrict__ hn_out,
    float* __restrict__ h, float* __restrict__ out, int last)
{
    const int r0  = blockIdx.x * 2;      // first row of this block
    const int b   = r0 >> 8;             // batch (2 divides 256 -> uniform)
    const int tid = threadIdx.x;
    const int w   = tid >> 6;            // wave 0..7
    const int lane = tid & 63;

    __shared__ int   snbr[2][MAXD];
    __shared__ int   sdeg[2];
    __shared__ float efeat[2][MAXD][EE];   // 8 KB
    __shared__ float part[8][MM];          // 2 KB
    __shared__ float smsg[2][MM];
    __shared__ float shold[2][FF];
    __shared__ float sx[2][FF];
    __shared__ float gI[2][3][FF], gH[2][3][FF];
    __shared__ float shnew[2][FF];
    __shared__ float sg[2][OUTD], se[2][OUTD];

    // ---- stage row state ----
    if (tid < 2) sdeg[tid] = deg[r0 + tid];
    if (tid < 2 * MAXD) {
        int r = tid >> 6;
        snbr[r][tid & 63] = nbr[(r0 + r) * MAXD + (tid & 63)];  // poison beyond deg never read
    }
    if (tid < 2 * FF) {
        int r = tid >> 6;
        shold[r][tid & 63] = h[(size_t)(r0 + r) * FF + (tid & 63)];
    }
    if (last && tid >= 2 * FF && tid < 4 * FF) {
        int r = (tid >> 6) & 1;
        sx[r][tid & 63] = nodes[(size_t)(r0 + r) * FF + (tid & 63)];
    }

    // W_e column (rows 64..79 of W_msg) -> registers
    float we[EE];
    #pragma unroll
    for (int k = 0; k < EE; ++k) we[k] = Wmsg[(FF + k) * MM + lane];
    __syncthreads();

    // ---- gather edge features into LDS ----
    #pragma unroll
    for (int r = 0; r < 2; ++r) {
        int cnt = sdeg[r] * EE;
        for (int i = tid; i < cnt; i += 512) {
            int slot = i >> 4, k = i & 15;
            efeat[r][slot][k] = edges[(((size_t)(r0 + r)) * NN + snbr[r][slot]) * EE + k];
        }
    }
    __syncthreads();

    // ---- message aggregation: waves 0-3 -> row 0, waves 4-7 -> row 1 ----
    {
        int r = w >> 2, sub = w & 3;
        int d = sdeg[r];
        const float* hb = hn_in + (size_t)b * NN * MM;
        float acc = 0.0f;
        for (int s = sub; s < d; s += 4) {
            int j = snbr[r][s];
            float term = hb[j * MM + lane];
            #pragma unroll
            for (int k = 0; k < EE; ++k) term += efeat[r][s][k] * we[k];
            acc += fmaxf(term, 0.0f);
        }
        part[w][lane] = acc;
    }
    __syncthreads();
    if ((w & 3) == 0) {
        int r = w >> 2;
        smsg[r][lane] = part[w][lane] + part[w + 1][lane]
                      + part[w + 2][lane] + part[w + 3][lane];
    }
    __syncthreads();

    // ---- GRU gates: wave q<3 -> gi gate q (both rows); q in 3..5 -> gh ----
    if (w < 3) {
        float a0 = bi[w * FF + lane], a1 = a0;
        #pragma unroll 4
        for (int k = 0; k < FF; ++k) {
            float wgt = Wi[k * G3 + w * FF + lane];
            a0 += smsg[0][k] * wgt;
            a1 += smsg[1][k] * wgt;
        }
        gI[0][w][lane] = a0; gI[1][w][lane] = a1;
    } else if (w < 6) {
        int g = w - 3;
        float a0 = bh[g * FF + lane], a1 = a0;
        #pragma unroll 4
        for (int k = 0; k < FF; ++k) {
            float wgt = Wh[k * G3 + g * FF + lane];
            a0 += shold[0][k] * wgt;
            a1 += shold[1][k] * wgt;
        }
        gH[0][g][lane] = a0; gH[1][g][lane] = a1;
    }
    __syncthreads();

    // ---- combine: 128 threads = 2 rows x 64 features ----
    if (tid < 2 * FF) {
        int r = tid >> 6, tt = tid & 63;
        float rr = sigmoidf_(gI[r][0][tt] + gH[r][0][tt]);
        float zz = sigmoidf_(gI[r][1][tt] + gH[r][1][tt]);
        float ng = tanhf(gI[r][2][tt] + rr * gH[r][2][tt]);
        float hold = shold[r][tt];
        float hnew = (1.0f - zz) * ng + zz * hold;
        if (sdeg[r] == 0) hnew = hold;       // node_mask scatter semantics
        shnew[r][tt] = hnew;
        h[(size_t)(r0 + r) * FF + tt] = hnew;
    }
    __syncthreads();

    if (!last) {
        // hn for next pass: h_new @ W_n + b_msg; wave w -> (row w>>2, k-quarter w&3)
        {
            int r = w >> 2, kq = w & 3;
            float p = 0.0f;
            #pragma unroll
            for (int kk = 0; kk < 16; ++kk) {
                int k = kq * 16 + kk;
                p += shnew[r][k] * Wmsg[k * MM + lane];
            }
            part[w][lane] = p;
        }
        __syncthreads();
        if (tid < 2 * MM) {
            int r = tid >> 6, tt = tid & 63;
            hn_out[(size_t)(r0 + r) * MM + tt] = bmsg[tt]
                + part[r*4+0][tt] + part[r*4+1][tt] + part[r*4+2][tt] + part[r*4+3][tt];
        }
    } else {
        // gated readout: 4 groups of 128 thr = (row, gate-vs-emb)
        int grp = tid >> 7, o = tid & 127;
        int r = grp >> 1, kind = grp & 1;
        if (kind == 0) {
            float g = bg[o];
            #pragma unroll 4
            for (int k = 0; k < FF; ++k) g += shnew[r][k] * Wg[k * OUTD + o];
            #pragma unroll 4
            for (int k = 0; k < FF; ++k) g += sx[r][k] * Wg[(FF + k) * OUTD + o];
            sg[r][o] = g;
        } else {
            float e = be[o];
            #pragma unroll 4
            for (int k = 0; k < FF; ++k) e += shnew[r][k] * We[k * OUTD + o];
            se[r][o] = e;
        }
        __syncthreads();
        if (tid < OUTD) {
            float v0 = (sdeg[0] != 0) ? sigmoidf_(sg[0][tid]) * se[0][tid] : 0.0f;
            float v1 = (sdeg[1] != 0) ? sigmoidf_(sg[1][tid]) * se[1][tid] : 0.0f;
            atomicAdd(&out[b * OUTD + tid], v0 + v1);
        }
    }
}

// ---------------------------------------------------------------------------
extern "C" void kernel_launch(void* const* d_in, const int* in_sizes, int n_in,
                              void* d_out, int out_size, void* d_ws, size_t ws_size,
                              hipStream_t stream) {
    const float* nodes = (const float*)d_in[0];
    const float* edges = (const float*)d_in[1];
    const float* Wmsg  = (const float*)d_in[2];
    const float* bmsg  = (const float*)d_in[3];
    const float* Wi    = (const float*)d_in[4];
    const float* Wh    = (const float*)d_in[5];
    const float* bi    = (const float*)d_in[6];
    const float* bh    = (const float*)d_in[7];
    const float* Wg    = (const float*)d_in[8];
    const float* bg    = (const float*)d_in[9];
    const float* We    = (const float*)d_in[10];
    const float* be    = (const float*)d_in[11];
    float* out = (float*)d_out;
    char* ws = (char*)d_ws;

    int*   deg  = (int*)ws;                                   // 8 KB
    int*   nbr  = (int*)(ws + 8192);                          // 512 KB
    float* h    = (float*)(ws + 8192 + (size_t)ROWS * MAXD * 4);
    float* hnA  = h   + (size_t)ROWS * FF;
    float* hnB  = hnA + (size_t)ROWS * MM;

    k_prep<<<ROWS, 256, 0, stream>>>(nodes, edges, Wmsg, bmsg, deg, nbr, h, hnA, out);

    // pass 0: hnA -> hnB ; pass 1: hnB -> hnA ; pass 2: hnA -> readout
    k_pass2<<<ROWS/2, 512, 0, stream>>>(edges, Wmsg, bmsg, Wi, Wh, bi, bh,
                                        nodes, Wg, bg, We, be, deg, nbr,
                                        hnA, hnB, h, out, 0);
    k_pass2<<<ROWS/2, 512, 0, stream>>>(edges, Wmsg, bmsg, Wi, Wh, bi, bh,
                                        nodes, Wg, bg, We, be, deg, nbr,
                                        hnB, hnA, h, out, 0);
    k_pass2<<<ROWS/2, 512, 0, stream>>>(edges, Wmsg, bmsg, Wi, Wh, bi, bh,
                                        nodes, Wg, bg, We, be, deg, nbr,
                                        hnA, hnB, h, out, 1);
}